// Round 18
// baseline (2396.492 us; speedup 1.0000x reference)
//
#include <hip/hip_runtime.h>
#include <hip/hip_bf16.h>
#include <math.h>

#define NN 10000
#define NE 160000
#define DIM 480
#define NSH 9
#define NBASIS 128
#define NHEAD 4
#define HDIM 120
#define NL 6
#define NG 256
#define NS 128
#define FCH 64
#define CUTOFF 5.0f
#define NEB 2500   // edge blocks (64 edges each)

typedef __attribute__((ext_vector_type(8))) short bf8v;
typedef __attribute__((ext_vector_type(4))) float f4v;

__device__ __forceinline__ float silu_f(float v) { return v / (1.0f + __expf(-v)); }
__device__ __forceinline__ float bf2f(ushort u) { return __uint_as_float(((unsigned)u) << 16); }
__device__ __forceinline__ ushort f2bfu(float f) {
  __hip_bfloat16 h = __float2bfloat16(f);
  return *reinterpret_cast<ushort*>(&h);
}

__device__ __forceinline__ void nt_store16(char* dst, uint4 v) {
  unsigned* p = (unsigned*)dst;
  __builtin_nontemporal_store(v.x, p + 0);
  __builtin_nontemporal_store(v.y, p + 1);
  __builtin_nontemporal_store(v.z, p + 2);
  __builtin_nontemporal_store(v.w, p + 3);
}
__device__ __forceinline__ uint4 nt_load16(const char* src) {
  const unsigned* p = (const unsigned*)src;
  uint4 v;
  v.x = __builtin_nontemporal_load(p + 0);
  v.y = __builtin_nontemporal_load(p + 1);
  v.z = __builtin_nontemporal_load(p + 2);
  v.w = __builtin_nontemporal_load(p + 3);
  return v;
}

struct bf16x4 { __hip_bfloat16 v[4]; };

// ---------------- CSR build ----------------
__global__ void k_zero_int(int* p, int n)
{
  int i = blockIdx.x * 256 + threadIdx.x;
  if (i < n) p[i] = 0;
}

__global__ void k_count(const int* __restrict__ edst, int* __restrict__ cnt)
{
  int e = blockIdx.x * 256 + threadIdx.x;
  if (e < NE) atomicAdd(&cnt[edst[e]], 1);
}

__global__ __launch_bounds__(1024)
void k_scan(const int* __restrict__ cnt, int* __restrict__ row_ptr)
{
  __shared__ int part[1024];
  int tid = threadIdx.x;
  const int per = 10;
  int base = tid * per;
  int s = 0;
  for (int i = 0; i < per; i++) { int idx = base + i; if (idx < NN) s += cnt[idx]; }
  part[tid] = s; __syncthreads();
  for (int off = 1; off < 1024; off <<= 1) {
    int v = (tid >= off) ? part[tid - off] : 0;
    __syncthreads();
    part[tid] += v;
    __syncthreads();
  }
  int run = (tid > 0) ? part[tid - 1] : 0;
  for (int i = 0; i < per; i++) {
    int idx = base + i;
    if (idx < NN) { row_ptr[idx] = run; run += cnt[idx]; }
  }
  if (tid == 1023) row_ptr[NN] = part[1023];
}

__global__ void k_fill(const int* __restrict__ edst, const int* __restrict__ row_ptr,
                       int* __restrict__ cursor, int* __restrict__ csr)
{
  int e = blockIdx.x * 256 + threadIdx.x;
  if (e >= NE) return;
  int d = edst[e];
  int p = atomicAdd(&cursor[d], 1);
  csr[row_ptr[d] + p] = e;
}

// ---------------- geometry in permuted (CSR) order; sh as bf16 [NE][16] padded ----
__global__ void k_geom_p(const float* __restrict__ pos, const int* __restrict__ esrc,
                         const int* __restrict__ edst, const int* __restrict__ csr,
                         __hip_bfloat16* __restrict__ shb, float* __restrict__ distp,
                         int* __restrict__ esrcp, int* __restrict__ edstp)
{
  int j = blockIdx.x * 256 + threadIdx.x;
  if (j >= NE) return;
  int e = csr[j];
  int s = esrc[e], d = edst[e];
  esrcp[j] = s;
  edstp[j] = d;
  float vx = pos[s*3+0] - pos[d*3+0];
  float vy = pos[s*3+1] - pos[d*3+1];
  float vz = pos[s*3+2] - pos[d*3+2];
  float r = sqrtf(vx*vx + vy*vy + vz*vz);
  distp[j] = r;
  float inv = 1.0f / (r + 1e-9f);
  float x = vx*inv, y = vy*inv, z = vz*inv;
  const float s3 = 1.7320508075688772f;
  const float s15 = 3.872983346207417f;
  const float s5 = 2.23606797749979f;
  float sv[9];
  sv[0] = 1.0f;
  sv[1] = s3*x; sv[2] = s3*y; sv[3] = s3*z;
  sv[4] = s15*x*y; sv[5] = s15*y*z; sv[6] = 0.5f*s5*(3.0f*z*z - 1.0f);
  sv[7] = s15*x*z; sv[8] = 0.5f*s15*(x*x - y*y);
  __hip_bfloat16* o = shb + (size_t)j * 16;
#pragma unroll
  for (int q = 0; q < 9; q++) o[q] = __float2bfloat16(sv[q]);
#pragma unroll
  for (int q = 9; q < 16; q++) o[q] = __float2bfloat16(0.f);
}

// ---------------- prep: w3T [7][512][64] + wshT [7][512][32] bf16 ----------------
__global__ void k_prep(const float* __restrict__ deg_w3, const float* __restrict__ rad_w3,
                       const float* __restrict__ W_deg_sh, const float* __restrict__ Wsh,
                       __hip_bfloat16* __restrict__ w3T, __hip_bfloat16* __restrict__ wshT)
{
  int i = blockIdx.x * 256 + threadIdx.x;
  if (i < 7*512*64) {
    int l = i / (512*64); int r = i - l*512*64; int col = r >> 6; int k = r & 63;
    float v = 0.f;
    if (col < DIM) {
      const float* src = (l == 0) ? deg_w3 : rad_w3 + (size_t)(l-1)*FCH*DIM;
      v = src[k*DIM + col];
    }
    w3T[i] = __float2bfloat16(v);
  }
  int j = i - 7*512*64;
  if (j >= 0 && j < 7*512*32) {
    int l = j / (512*32); int r = j - l*512*32; int col = r >> 5; int q = r & 31;
    float v = 0.f;
    if (col < DIM && q < 9) {
      const float* src = (l == 0) ? W_deg_sh : Wsh + (size_t)(l-1)*NSH*DIM;
      v = src[q*DIM + col];
    }
    wshT[j] = __float2bfloat16(v);
  }
}

// ---------------- prep: node-GEMM weights transposed bf16 ----------------
__global__ void k_prepw(const float* __restrict__ Wv, const float* __restrict__ Wo,
                        const float* __restrict__ f1, const float* __restrict__ f2,
                        const float* __restrict__ h1, const float* __restrict__ h2w,
                        __hip_bfloat16* __restrict__ WT)
{
  int i = blockIdx.x * 256 + threadIdx.x;
  const int big = 24*512*480;
  if (i < big) {
    int m = i / (512*480); int r = i - m*(512*480); int col = r / 480; int k = r - col*480;
    int l = m % 6; int t = m / 6;
    const float* src = (t==0 ? Wv : t==1 ? Wo : t==2 ? f1 : f2) + (size_t)l*DIM*DIM;
    float v = (col < DIM) ? src[k*DIM + col] : 0.f;
    WT[i] = __float2bfloat16(v);
  } else if (i < big + 2*128*128) {
    int j = i - big; int m = j / (128*128); int r = j - m*(128*128);
    int col = r >> 7; int k = r & 127;
    const float* src = m ? h2w : h1;
    WT[i] = __float2bfloat16(src[k*128 + col]);
  }
}

// ---------------- radial MLP -> h2 bf16 [E,64] ----------------
__global__ __launch_bounds__(256)
void k_radial(const float* __restrict__ dist, const float* __restrict__ w1,
              const float* __restrict__ w2, __hip_bfloat16* __restrict__ h2out)
{
  __shared__ float rbs[NBASIS][65];
  __shared__ float wsm[NBASIS * FCH];
  __shared__ float ds[64];
  int tid = threadIdx.x;
  int e0 = blockIdx.x * 64;
  if (tid < 64) ds[tid] = dist[e0 + tid];
  for (int i = tid; i < NBASIS * FCH; i += 256) wsm[i] = w1[i];
  __syncthreads();
  const float invw = (float)NBASIS / CUTOFF;
  for (int i = tid; i < NBASIS * 64; i += 256) {
    int k = i >> 6, e = i & 63;
    float c = k * (CUTOFF / 127.0f);
    float tt = (ds[e] - c) * invw;
    rbs[k][e] = __expf(-0.5f * tt * tt);
  }
  __syncthreads();
  int ty = tid >> 4, tx = tid & 15;
  float acc1[4][4] = {};
  for (int k = 0; k < NBASIS; k++) {
    float b[4];
#pragma unroll
    for (int j = 0; j < 4; j++) b[j] = wsm[k*FCH + tx*4 + j];
#pragma unroll
    for (int i = 0; i < 4; i++) {
      float a = rbs[k][ty*4 + i];
#pragma unroll
      for (int j = 0; j < 4; j++) acc1[i][j] = fmaf(a, b[j], acc1[i][j]);
    }
  }
  __syncthreads();
#pragma unroll
  for (int i = 0; i < 4; i++)
#pragma unroll
    for (int j = 0; j < 4; j++)
      rbs[tx*4 + j][ty*4 + i] = silu_f(acc1[i][j]);
  for (int i = tid; i < FCH * FCH; i += 256) wsm[i] = w2[i];
  __syncthreads();
  float acc2[4][4] = {};
  for (int k = 0; k < FCH; k++) {
    float b[4];
#pragma unroll
    for (int j = 0; j < 4; j++) b[j] = wsm[k*FCH + tx*4 + j];
#pragma unroll
    for (int i = 0; i < 4; i++) {
      float a = rbs[k][ty*4 + i];
#pragma unroll
      for (int j = 0; j < 4; j++) acc2[i][j] = fmaf(a, b[j], acc2[i][j]);
    }
  }
#pragma unroll
  for (int i = 0; i < 4; i++) {
    int e = e0 + ty*4 + i;
    bf16x4 p;
#pragma unroll
    for (int j = 0; j < 4; j++) p.v[j] = __float2bfloat16(silu_f(acc2[i][j]));
    *(bf16x4*)(h2out + (size_t)e*FCH + tx*4) = p;
  }
}

// ---------------- per-row LN stats (mu, rstd) — full read (init + head only) ----
__global__ __launch_bounds__(256)
void k_stats(const float* __restrict__ in, float* __restrict__ st,
             int n, int cols, int stride)
{
  int row = blockIdx.x * 4 + (threadIdx.x >> 6);
  int lane = threadIdx.x & 63;
  if (row >= n) return;
  const float* r = in + (size_t)row * stride;
  float s = 0.f, ss = 0.f;
  for (int c = lane; c < cols; c += 64) { float v = r[c]; s += v; ss += v*v; }
  for (int off = 32; off > 0; off >>= 1) { s += __shfl_down(s, off); ss += __shfl_down(ss, off); }
  if (lane == 0) {
    float mu = s / cols;
    float var = ss / cols - mu * mu;
    st[row*2]   = mu;
    st[row*2+1] = rsqrtf(fmaxf(var, 0.f) + 1e-5f);
  }
}

// ---------------- finalize fused stats: (sum,sumsq) -> (mu, rstd) ----------------
__global__ void k_finstat(const float* __restrict__ stacc, float* __restrict__ st, int n)
{
  int row = blockIdx.x * 256 + threadIdx.x;
  if (row >= n) return;
  float s = stacc[row*2], ss = stacc[row*2+1];
  float mu = s / DIM;
  float var = ss / DIM - mu * mu;
  st[row*2]   = mu;
  st[row*2+1] = rsqrtf(fmaxf(var, 0.f) + 1e-5f);
}

// ---------------- MFMA node GEMM: 64 rows x 128 cols; STATS=1 accumulates row
// (sum,sumsq) partials of the written x into stacc via atomics ----------------
template<int ADD, int SILU, int LNA, int OBF16, int STATS>
__global__ __launch_bounds__(256)
void k_gemmm(const float* __restrict__ A, const __hip_bfloat16* __restrict__ BT,
             float* __restrict__ C, __hip_bfloat16* __restrict__ Cb,
             const float* __restrict__ st, int M, int K, int Nc, int lda,
             float* __restrict__ stacc)
{
  __shared__ __align__(16) char smA[4096];
  __shared__ __align__(16) char smB[8192];
  __shared__ float smu[64], srs[64];
  int tid = threadIdx.x;
  int lane = tid & 63;
  int wv = tid >> 6;
  int l15 = lane & 15, l4 = lane >> 4;
  int row0 = blockIdx.x * 64;
  int col0 = blockIdx.y * 128;
  if (LNA && tid < 64) {
    int gr = row0 + tid;
    float m2 = 0.f, r2 = 1.f;
    if (gr < M) { m2 = st[gr*2]; r2 = st[gr*2+1]; }
    smu[tid] = m2; srs[tid] = r2;
  }
  f4v z4 = {0.f,0.f,0.f,0.f};
  f4v acc[8];
#pragma unroll
  for (int ct = 0; ct < 8; ct++) acc[ct] = z4;

  int arow = tid >> 2, aq = tid & 3;
  int bcol = tid >> 1, bh = tid & 1;
  for (int k0 = 0; k0 < K; k0 += 32) {
    __syncthreads();
    {
      int grow = row0 + arow;
      float f[8];
      if (grow < M) {
        const float* ap = A + (size_t)grow * lda + k0 + aq*8;
        float4 v0 = *(const float4*)ap;
        float4 v1 = *(const float4*)(ap + 4);
        f[0]=v0.x; f[1]=v0.y; f[2]=v0.z; f[3]=v0.w;
        f[4]=v1.x; f[5]=v1.y; f[6]=v1.z; f[7]=v1.w;
      } else {
#pragma unroll
        for (int q = 0; q < 8; q++) f[q] = 0.f;
      }
      if (LNA) {
        float mu = smu[arow], rs = srs[arow];
#pragma unroll
        for (int q = 0; q < 8; q++) f[q] = (f[q] - mu) * rs;
      }
      unsigned u[4];
#pragma unroll
      for (int q = 0; q < 4; q++)
        u[q] = (unsigned)f2bfu(f[2*q]) | ((unsigned)f2bfu(f[2*q+1]) << 16);
      int base = arow*64 + aq*16;
      *(uint4*)(smA + (base ^ ((arow&7)<<4))) = make_uint4(u[0],u[1],u[2],u[3]);
    }
    {
      const ushort* bp = (const ushort*)BT + (size_t)(col0 + bcol) * K + k0 + bh*16;
      uint4 v0 = *(const uint4*)bp;
      uint4 v1 = *(const uint4*)(bp + 8);
      int base = bcol*64 + bh*32;
      *(uint4*)(smB + (base ^ ((bcol&7)<<4))) = v0;
      *(uint4*)(smB + ((base+16) ^ ((bcol&7)<<4))) = v1;
    }
    __syncthreads();
    int r0 = wv*16 + l15;
    bf8v a0 = *(const bf8v*)(smA + ((r0*64 + l4*16) ^ ((r0&7)<<4)));
#pragma unroll
    for (int ct = 0; ct < 8; ct++) {
      int cc = ct*16 + l15;
      bf8v b = *(const bf8v*)(smB + ((cc*64 + l4*16) ^ ((cc&7)<<4)));
      acc[ct] = __builtin_amdgcn_mfma_f32_16x16x32_bf16(a0, b, acc[ct], 0, 0, 0);
    }
  }
#pragma unroll
  for (int e = 0; e < 4; e++) {
    int row = row0 + wv*16 + l4*4 + e;
    float s = 0.f, ss = 0.f;
#pragma unroll
    for (int ct = 0; ct < 8; ct++) {
      int col = col0 + ct*16 + l15;
      if (row < M && col < Nc) {
        float v = acc[ct][e];
        if (SILU) v = silu_f(v);
        if (OBF16) Cb[(size_t)row * Nc + col] = __float2bfloat16(v);
        else {
          float* p = C + (size_t)row * Nc + col;
          float xn = ADD ? (*p + v) : v;
          *p = xn;
          if (STATS) { s += xn; ss += xn * xn; }
        }
      }
    }
    if (STATS) {
#pragma unroll
      for (int off = 1; off < 16; off <<= 1) {
        s  += __shfl_xor(s,  off, 16);
        ss += __shfl_xor(ss, off, 16);
      }
      if (l15 == 0 && row < M) {
        atomicAdd(&stacc[row*2],   s);
        atomicAdd(&stacc[row*2+1], ss);
      }
    }
  }
}

// ---------------- MFMA msg kernel, col-fused (round 17, unchanged) ----------------
template<int MODE, int STOREM>
__global__ __launch_bounds__(256)
void k_msgm(const __hip_bfloat16* __restrict__ h2, const __hip_bfloat16* __restrict__ shb,
            const int* __restrict__ esrcp, const int* __restrict__ edstp,
            const __hip_bfloat16* __restrict__ w3T, const __hip_bfloat16* __restrict__ wshT,
            const float* __restrict__ aa, const __hip_bfloat16* __restrict__ y,
            const float* __restrict__ alpha, float* __restrict__ outbuf,
            float* __restrict__ logits, __hip_bfloat16* __restrict__ msgb)
{
  __shared__ __align__(16) char sm_h2[8192];
  __shared__ __align__(16) char sm_w3[16384];
  __shared__ __align__(16) char sm_sh[4096];
  __shared__ __align__(16) char sm_wsh[8192];
  __shared__ int srcs[(MODE<=1)?64:1];
  __shared__ int dsts[(MODE>=1)?64:1];
  __shared__ int segidL[(MODE>=1)?64:1];
  __shared__ int seg_dstL[(MODE>=1)?32:1];

  int bid = blockIdx.x;
  int xcd = bid & 7;
  const int qq = NEB >> 3, rr = NEB & 7;
  int basee = (xcd < rr) ? xcd * (qq + 1) : rr * (qq + 1) + (xcd - rr) * qq;
  int eblk = basee + (bid >> 3);
  int e0 = eblk * 64;

  int tid = threadIdx.x;
  int lane = tid & 63;
  int wv = tid >> 6;
  int l15 = lane & 15, l4 = lane >> 4;
  int wrow0 = wv * 16;

  for (int c = tid; c < 512; c += 256) {
    int r = c >> 3, s = c & 7;
    uint4 v = *(const uint4*)((const char*)h2 + (size_t)(e0 + r) * 128 + s * 16);
    *(uint4*)(sm_h2 + ((r * 128 + s * 16) ^ ((r & 7) << 4))) = v;
  }
  {
    int r = tid >> 2, q = tid & 3;
    uint4 v = make_uint4(0u, 0u, 0u, 0u);
    if (q < 2)
      v = *(const uint4*)((const ushort*)shb + (size_t)(e0 + r) * 16 + q * 8);
    *(uint4*)(sm_sh + ((r * 64 + q * 16) ^ ((r & 7) << 4))) = v;
  }
  if (tid < 64) {
    if (MODE <= 1) srcs[tid] = esrcp[e0 + tid];
    if (MODE >= 1) dsts[tid] = edstp[e0 + tid];
  }
  __syncthreads();

  int nseg = 0;
  if (MODE >= 1) {
    if (tid < 64) {
      bool flag = (tid == 0) || (dsts[tid] != dsts[tid - 1]);
      unsigned long long m = __ballot(flag ? 1 : 0);
      unsigned long long below = m & (~0ull >> (63 - tid));
      int sg = __popcll(below) - 1;
      segidL[tid] = sg;
      if (flag && sg < 32) seg_dstL[sg] = dsts[tid];
    }
    __syncthreads();
    nseg = segidL[63] + 1;
  }

  int srcs4[4];
  float4 al4[4];
#pragma unroll
  for (int e = 0; e < 4; e++) {
    int rl = wrow0 + l4 * 4 + e;
    if (MODE <= 1) srcs4[e] = srcs[rl];
    if (MODE == 1) al4[e] = *(const float4*)(alpha + (size_t)(e0 + rl) * 4);
  }

  const ushort* yus = (const ushort*)y;
  f4v z4 = {0.f, 0.f, 0.f, 0.f};
  float lacc[4][4];
  if (MODE == 0) {
#pragma unroll
    for (int e = 0; e < 4; e++)
#pragma unroll
      for (int h = 0; h < 4; h++) lacc[e][h] = 0.f;
  }

#pragma unroll
  for (int ci = 0; ci < 4; ci++) {
    int col0 = ci * 128;
    __syncthreads();
    for (int c = tid; c < 1024; c += 256) {
      int r = c >> 3, s = c & 7;
      uint4 v = *(const uint4*)((const char*)w3T + (size_t)(col0 + r) * 128 + s * 16);
      *(uint4*)(sm_w3 + ((r * 128 + s * 16) ^ ((r & 7) << 4))) = v;
    }
    for (int c = tid; c < 512; c += 256) {
      int r = c >> 2, q = c & 3;
      uint4 v = *(const uint4*)((const ushort*)wshT + (size_t)(col0 + r) * 32 + q * 8);
      *(uint4*)(sm_wsh + ((r * 64 + q * 16) ^ ((r & 7) << 4))) = v;
    }
    __syncthreads();

    f4v g[8];
#pragma unroll
    for (int ct = 0; ct < 8; ct++) g[ct] = z4;

#pragma unroll
    for (int ks = 0; ks < 2; ks++) {
      int k0b = (ks * 32 + l4 * 8) * 2;
      int r0 = wrow0 + l15;
      bf8v a0 = *(const bf8v*)(sm_h2 + ((r0 * 128 + k0b) ^ ((r0 & 7) << 4)));
#pragma unroll
      for (int ct = 0; ct < 8; ct++) {
        int cc = ct * 16 + l15;
        bf8v b = *(const bf8v*)(sm_w3 + ((cc * 128 + k0b) ^ ((cc & 7) << 4)));
        g[ct] = __builtin_amdgcn_mfma_f32_16x16x32_bf16(a0, b, g[ct], 0, 0, 0);
      }
    }

    {
      int r0 = wrow0 + l15;
      bf8v shA = *(const bf8v*)(sm_sh + ((r0 * 64 + l4 * 16) ^ ((r0 & 7) << 4)));
#pragma unroll
      for (int ct = 0; ct < 8; ct++) {
        int cc = ct * 16 + l15;
        int col = col0 + cc;
        bf8v wB = *(const bf8v*)(sm_wsh + ((cc * 64 + l4 * 16) ^ ((cc & 7) << 4)));
        f4v sw4 = __builtin_amdgcn_mfma_f32_16x16x32_bf16(shA, wB, z4, 0, 0, 0);
#pragma unroll
        for (int e = 0; e < 4; e++) {
          float yv;
          if (MODE == 2) yv = 1.f;
          else yv = (col < DIM) ? bf2f(yus[(size_t)srcs4[e] * DIM + col]) : 0.f;
          float mv = yv * sw4[e] * g[ct][e];
          if (MODE == 1) {
            float av = (col < 120) ? al4[e].x : (col < 240) ? al4[e].y
                     : (col < 360) ? al4[e].z : al4[e].w;
            mv *= av;
          }
          if (MODE == 2) mv *= (1.0f / 16.0f);
          g[ct][e] = mv;
        }
      }
    }

    if (MODE == 0) {
      float aav[8];
#pragma unroll
      for (int ct = 0; ct < 8; ct++) {
        int col = col0 + ct * 16 + l15;
        aav[ct] = (col < DIM) ? aa[col] : 0.f;
      }
#pragma unroll
      for (int e = 0; e < 4; e++) {
        float sA = 0.f, sB = 0.f;
#pragma unroll
        for (int ct = 0; ct < 8; ct++) {
          int col = col0 + ct * 16 + l15;
          float mv = g[ct][e];
          float lv = (mv > 0.f) ? mv : 0.2f * mv;
          float c = lv * aav[ct];
          if (col / 120 == ci) sA += c; else sB += c;
        }
#pragma unroll
        for (int off = 1; off < 16; off <<= 1) {
          sA += __shfl_xor(sA, off, 16);
          sB += __shfl_xor(sB, off, 16);
        }
        lacc[e][ci] += sA;
        if (ci < 3) lacc[e][ci + 1] += sB;
      }
      if (STOREM) {
        __syncthreads();
#pragma unroll
        for (int ct = 0; ct < 8; ct++) {
          int cc = ct * 16 + l15;
          int ebase = wrow0 + l4 * 4;
          ushort4 pk;
          pk.x = f2bfu(g[ct][0]); pk.y = f2bfu(g[ct][1]);
          pk.z = f2bfu(g[ct][2]); pk.w = f2bfu(g[ct][3]);
          *(ushort4*)(sm_w3 + ((cc * 128 + ebase * 2) ^ ((cc & 7) << 4))) = pk;
        }
        __syncthreads();
        char* gdst = (char*)msgb + (size_t)(eblk * 4 + ci) * 16384;
#pragma unroll
        for (int k = 0; k < 4; k++) {
          int o = tid * 16 + k * 4096;
          uint4 v = *(const uint4*)(sm_w3 + o);
          nt_store16(gdst + o, v);
        }
      }
    } else if (nseg > 32) {
#pragma unroll
      for (int e = 0; e < 4; e++) {
        int rl = wrow0 + l4 * 4 + e;
        int dd = dsts[rl];
#pragma unroll
        for (int ct = 0; ct < 8; ct++) {
          int col = col0 + ct * 16 + l15;
          if (col < DIM) atomicAdd(&outbuf[(size_t)dd * DIM + col], g[ct][e]);
        }
      }
    } else {
      __syncthreads();
#pragma unroll
      for (int ct = 0; ct < 8; ct++) {
        int cc = ct * 16 + l15;
        int ebase = wrow0 + l4 * 4;
        ushort4 pk;
        pk.x = f2bfu(g[ct][0]); pk.y = f2bfu(g[ct][1]);
        pk.z = f2bfu(g[ct][2]); pk.w = f2bfu(g[ct][3]);
        *(ushort4*)(sm_w3 + ((cc * 128 + ebase * 2) ^ ((cc & 7) << 4))) = pk;
      }
      __syncthreads();
      f4v p[2][2];
      p[0][0] = z4; p[0][1] = z4; p[1][0] = z4; p[1][1] = z4;
#pragma unroll
      for (int ks = 0; ks < 2; ks++) {
        int k0 = ks * 32 + l4 * 8;
        bf8v a0, a1;
#pragma unroll
        for (int e2 = 0; e2 < 8; e2++) {
          int sg = segidL[k0 + e2];
          a0[e2] = (sg == l15)      ? (short)0x3F80 : (short)0;
          a1[e2] = (sg == l15 + 16) ? (short)0x3F80 : (short)0;
        }
#pragma unroll
        for (int c2 = 0; c2 < 2; c2++) {
          int cc = (wv * 2 + c2) * 16 + l15;
          bf8v bm = *(const bf8v*)(sm_w3 + ((cc * 128 + k0 * 2) ^ ((cc & 7) << 4)));
          p[0][c2] = __builtin_amdgcn_mfma_f32_16x16x32_bf16(a0, bm, p[0][c2], 0, 0, 0);
          p[1][c2] = __builtin_amdgcn_mfma_f32_16x16x32_bf16(a1, bm, p[1][c2], 0, 0, 0);
        }
      }
#pragma unroll
      for (int rt = 0; rt < 2; rt++)
#pragma unroll
      for (int c2 = 0; c2 < 2; c2++)
#pragma unroll
      for (int e = 0; e < 4; e++) {
        int seg = rt * 16 + l4 * 4 + e;
        int col = col0 + (wv * 2 + c2) * 16 + l15;
        if (seg < nseg && col < DIM) {
          float v = p[rt][c2][e];
          float* ptr = outbuf + (size_t)seg_dstL[seg] * DIM + col;
          if (seg == 0 || seg == nseg - 1) atomicAdd(ptr, v);
          else if (MODE == 1) *ptr = v;
          else *ptr += v;
        }
      }
    }
  }

  if (MODE == 0) {
#pragma unroll
    for (int e = 0; e < 4; e++) {
      int row = e0 + wrow0 + l4 * 4 + e;
      if (l15 == 0) {
        logits[(size_t)row * 4 + 0] = lacc[e][0];
        logits[(size_t)row * 4 + 1] = lacc[e][1];
        logits[(size_t)row * 4 + 2] = lacc[e][2];
        logits[(size_t)row * 4 + 3] = lacc[e][3];
      }
    }
  }
}

// ---------------- pass B, col-fused: 2500 blocks x 4 chunks ----------------
__global__ __launch_bounds__(256)
void k_aggm(const __hip_bfloat16* __restrict__ msgb, const int* __restrict__ edstp,
            const float* __restrict__ alpha, float* __restrict__ agg)
{
  __shared__ __align__(16) char smM[16384];
  __shared__ __align__(16) float alsq[64][4];
  __shared__ int dsts[64];
  __shared__ int segidL[64];
  __shared__ int seg_dstL[32];

  int bid = blockIdx.x;
  int xcd = bid & 7;
  const int qq = NEB >> 3, rr = NEB & 7;
  int basee = (xcd < rr) ? xcd * (qq + 1) : rr * (qq + 1) + (xcd - rr) * qq;
  int eblk = basee + (bid >> 3);
  int e0 = eblk * 64;

  int tid = threadIdx.x;
  int lane = tid & 63;
  int wv = tid >> 6;
  int l15 = lane & 15, l4 = lane >> 4;

  if (tid < 64) {
    dsts[tid] = edstp[e0 + tid];
    *(float4*)&alsq[tid][0] = *(const float4*)(alpha + (size_t)(e0 + tid) * 4);
  }
  __syncthreads();

  int nseg = 0;
  if (tid < 64) {
    bool flag = (tid == 0) || (dsts[tid] != dsts[tid - 1]);
    unsigned long long m = __ballot(flag ? 1 : 0);
    unsigned long long below = m & (~0ull >> (63 - tid));
    int sg = __popcll(below) - 1;
    segidL[tid] = sg;
    if (flag && sg < 32) seg_dstL[sg] = dsts[tid];
  }
  __syncthreads();
  nseg = segidL[63] + 1;

  f4v z4 = {0.f,0.f,0.f,0.f};
#pragma unroll
  for (int ci = 0; ci < 4; ci++) {
    int col0 = ci * 128;
    __syncthreads();                               // prior chunk MFMA reads done
    const char* gsrc = (const char*)msgb + (size_t)(eblk * 4 + ci) * 16384;
    uint4 vv[4];
#pragma unroll
    for (int k = 0; k < 4; k++) {
      int o = tid * 16 + k * 4096;
      uint4 v = nt_load16(gsrc + o);
      int cc = o >> 7;
      int col = col0 + cc;
      int h = (col < DIM) ? (col / 120) : 3;
      int be = ((o & 127) ^ ((cc & 7) << 4)) >> 1;
      unsigned w[4] = {v.x, v.y, v.z, v.w};
#pragma unroll
      for (int q = 0; q < 4; q++) {
        float lo = bf2f((ushort)(w[q] & 0xffffu)) * alsq[be + 2*q][h];
        float hi = bf2f((ushort)(w[q] >> 16))     * alsq[be + 2*q + 1][h];
        w[q] = (unsigned)f2bfu(lo) | ((unsigned)f2bfu(hi) << 16);
      }
      vv[k] = make_uint4(w[0], w[1], w[2], w[3]);
      *(uint4*)(smM + o) = vv[k];
    }
    __syncthreads();

    if (nseg > 32) {
#pragma unroll
      for (int k = 0; k < 4; k++) {
        int o = tid * 16 + k * 4096;
        int cc = o >> 7;
        int col = col0 + cc;
        if (col >= DIM) continue;
        int be = ((o & 127) ^ ((cc & 7) << 4)) >> 1;
        unsigned w[4] = {vv[k].x, vv[k].y, vv[k].z, vv[k].w};
#pragma unroll
        for (int q = 0; q < 4; q++) {
          atomicAdd(&agg[(size_t)dsts[be + 2*q]   * DIM + col], bf2f((ushort)(w[q] & 0xffffu)));
          atomicAdd(&agg[(size_t)dsts[be + 2*q+1] * DIM + col], bf2f((ushort)(w[q] >> 16)));
        }
      }
      continue;
    }

    f4v p[2][2];
    p[0][0] = z4; p[0][1] = z4; p[1][0] = z4; p[1][1] = z4;
#pragma unroll
    for (int ks = 0; ks < 2; ks++) {
      int k0 = ks * 32 + l4 * 8;
      bf8v a0, a1;
#pragma unroll
      for (int e2 = 0; e2 < 8; e2++) {
        int sg = segidL[k0 + e2];
        a0[e2] = (sg == l15)      ? (short)0x3F80 : (short)0;
        a1[e2] = (sg == l15 + 16) ? (short)0x3F80 : (short)0;
      }
#pragma unroll
      for (int c2 = 0; c2 < 2; c2++) {
        int cc = (wv * 2 + c2) * 16 + l15;
        bf8v bm = *(const bf8v*)(smM + ((cc * 128 + k0 * 2) ^ ((cc & 7) << 4)));
        p[0][c2] = __builtin_amdgcn_mfma_f32_16x16x32_bf16(a0, bm, p[0][c2], 0, 0, 0);
        p[1][c2] = __builtin_amdgcn_mfma_f32_16x16x32_bf16(a1, bm, p[1][c2], 0, 0, 0);
      }
    }
#pragma unroll
    for (int rt = 0; rt < 2; rt++)
#pragma unroll
    for (int c2 = 0; c2 < 2; c2++)
#pragma unroll
    for (int e = 0; e < 4; e++) {
      int seg = rt * 16 + l4 * 4 + e;
      int col = col0 + (wv * 2 + c2) * 16 + l15;
      if (seg < nseg && col < DIM) {
        float v = p[rt][c2][e];
        float* ptr = agg + (size_t)seg_dstL[seg] * DIM + col;
        if (seg == 0 || seg == nseg - 1) atomicAdd(ptr, v);
        else *ptr = v;
      }
    }
  }
}

// ---------------- segment softmax ----------------
__global__ void k_alpha(const int* __restrict__ row_ptr, const float* __restrict__ logits,
                        float* __restrict__ alpha)
{
  int i = blockIdx.x * 256 + threadIdx.x;
  if (i >= NN * NHEAD) return;
  int d = i >> 2, h = i & 3;
  int beg = row_ptr[d], end = row_ptr[d+1];
  if (beg == end) return;
  float m = -1e30f;
  for (int j = beg; j < end; j++) m = fmaxf(m, logits[(size_t)j*NHEAD + h]);
  float s = 0.f;
  for (int j = beg; j < end; j++) {
    float ex = __expf(logits[(size_t)j*NHEAD + h] - m);
    alpha[(size_t)j*NHEAD + h] = ex;
    s += ex;
  }
  float inv = 1.f / (s + 1e-9f);
  for (int j = beg; j < end; j++) alpha[(size_t)j*NHEAD + h] *= inv;
}

// ---------------- x init ----------------
__global__ void k_init_x(const int* __restrict__ z, const float* __restrict__ emb,
                         float* __restrict__ x)
{
  int i = blockIdx.x * 256 + threadIdx.x;
  if (i >= NN * DIM) return;
  int n = i / DIM, c = i - n * DIM;
  x[i] = emb[(size_t)z[n]*DIM + c];
}

// ---------------- final scatter ----------------
__global__ void k_scatter(const float* __restrict__ h, const int* __restrict__ batch,
                          float* __restrict__ out)
{
  int i = blockIdx.x * 256 + threadIdx.x;
  if (i >= NN * NS) return;
  int n = i >> 7;
  atomicAdd(&out[(size_t)batch[n]*NS + (i & 127)], h[i] * 0.23570226039551584f);
}

extern "C" void kernel_launch(void* const* d_in, const int* in_sizes, int n_in,
                              void* d_out, int out_size, void* d_ws, size_t ws_size,
                              hipStream_t stream)
{
  const int*   z        = (const int*)  d_in[0];
  const float* pos      = (const float*)d_in[1];
  const int*   batch    = (const int*)  d_in[2];
  const int*   esrc     = (const int*)  d_in[3];
  const int*   edst     = (const int*)  d_in[4];
  const float* atom_emb = (const float*)d_in[5];
  const float* W_deg_sh = (const float*)d_in[6];
  const float* deg_w1   = (const float*)d_in[7];
  const float* deg_w2   = (const float*)d_in[8];
  const float* deg_w3   = (const float*)d_in[9];
  const float* Wv       = (const float*)d_in[10];
  const float* Wsh      = (const float*)d_in[11];
  const float* rad_w1   = (const float*)d_in[12];
  const float* rad_w2   = (const float*)d_in[13];
  const float* rad_w3   = (const float*)d_in[14];
  const float* attn_a   = (const float*)d_in[15];
  const float* Wo       = (const float*)d_in[16];
  const float* ffn_w1   = (const float*)d_in[17];
  const float* ffn_w2   = (const float*)d_in[18];
  const float* head_w1  = (const float*)d_in[19];
  const float* head_w2  = (const float*)d_in[20];
  float* out = (float*)d_out;

  float* x      = (float*)d_ws;
  float* statsb = x      + (size_t)NN * DIM;          // [NN][2]
  float* stacc  = statsb + (size_t)NN * 2;            // [NN][2] fused-stats accum
  float* agg    = stacc  + (size_t)NN * 2;            // [NN][480]
  float* distp  = agg    + (size_t)NN * DIM;
  float* logitsb= distp  + (size_t)NE;                // [NE][4] used; NE*8 reserved (tmp overlay)
  float* alphab = logitsb+ (size_t)NE * NHEAD * 2;
  __hip_bfloat16* yb    = (__hip_bfloat16*)(alphab + (size_t)NE * NHEAD);
  __hip_bfloat16* h2b   = yb + (size_t)NN * DIM;
  __hip_bfloat16* shb16 = h2b + (size_t)NE * FCH;
  __hip_bfloat16* w3Tb  = shb16 + (size_t)NE * 16;
  __hip_bfloat16* wshTb = w3Tb + (size_t)7 * 512 * 64;
  __hip_bfloat16* bigWT = wshTb + (size_t)7 * 512 * 32;
  int* cnt      = (int*)(bigWT + (size_t)24*512*480 + 2*128*128);
  int* row_ptr  = cnt + NN;
  int* csr      = row_ptr + NN + 1;
  int* cursor   = csr + NE;
  int* esrcp    = cursor + NN;
  int* edstp    = esrcp + NE;
  __hip_bfloat16* msgb = (__hip_bfloat16*)(edstp + NE);
  float* tmp = logitsb;

  size_t needed = (size_t)((char*)msgb + (size_t)10000 * 16384 - (char*)d_ws);
  bool fast = ws_size >= needed;

  dim3 b256(256);
  k_zero_int<<<(NN+255)/256, b256, 0, stream>>>(cnt, NN);
  k_count<<<(NE+255)/256, b256, 0, stream>>>(edst, cnt);
  k_scan<<<1, 1024, 0, stream>>>(cnt, row_ptr);
  k_zero_int<<<(NN+255)/256, b256, 0, stream>>>(cursor, NN);
  k_fill<<<(NE+255)/256, b256, 0, stream>>>(edst, row_ptr, cursor, csr);
  k_geom_p<<<(NE+255)/256, b256, 0, stream>>>(pos, esrc, edst, csr, shb16, distp, esrcp, edstp);
  k_prep<<<(7*512*64 + 7*512*32 + 255)/256, b256, 0, stream>>>(deg_w3, rad_w3, W_deg_sh, Wsh,
      w3Tb, wshTb);
  k_prepw<<<(24*512*480 + 2*128*128 + 255)/256, b256, 0, stream>>>(Wv, Wo, ffn_w1, ffn_w2,
      head_w1, head_w2, bigWT);

  // degree embedding
  k_radial<<<NE/64, b256, 0, stream>>>(distp, deg_w1, deg_w2, h2b);
  k_init_x<<<(NN*DIM+255)/256, b256, 0, stream>>>(z, atom_emb, x);
  k_msgm<2,0><<<NEB, b256, 0, stream>>>(h2b, shb16, esrcp, edstp, w3Tb, wshTb,
      nullptr, nullptr, nullptr, x, nullptr, nullptr);
  k_stats<<<(NN+3)/4, b256, 0, stream>>>(x, statsb, NN, DIM, DIM);   // initial stats

  dim3 gemm_grid(157, 4);
  dim3 head_grid(157, 1);
  for (int l = 0; l < NL; l++) {
    const float* w1_l  = rad_w1 + (size_t)l*NBASIS*FCH;
    const float* w2_l  = rad_w2 + (size_t)l*FCH*FCH;
    const float* aa_l  = attn_a + (size_t)l*NHEAD*HDIM;
    const __hip_bfloat16* w3T_l  = w3Tb  + (size_t)(l+1)*512*64;
    const __hip_bfloat16* wshT_l = wshTb + (size_t)(l+1)*512*32;
    const __hip_bfloat16* WvT_l = bigWT + (size_t)(0+l)*512*480;
    const __hip_bfloat16* WoT_l = bigWT + (size_t)(6+l)*512*480;
    const __hip_bfloat16* F1T_l = bigWT + (size_t)(12+l)*512*480;
    const __hip_bfloat16* F2T_l = bigWT + (size_t)(18+l)*512*480;

    k_gemmm<0,0,1,1,0><<<gemm_grid, b256, 0, stream>>>(x, WvT_l, nullptr, yb, statsb,
        NN, DIM, DIM, DIM, nullptr);
    k_radial<<<NE/64, b256, 0, stream>>>(distp, w1_l, w2_l, h2b);
    if (fast) {
      k_msgm<0,1><<<NEB, b256, 0, stream>>>(h2b, shb16, esrcp, edstp, w3T_l, wshT_l,
          aa_l, yb, nullptr, nullptr, logitsb, msgb);
      k_alpha<<<(NN*NHEAD+255)/256, b256, 0, stream>>>(row_ptr, logitsb, alphab);
      hipMemsetAsync(agg, 0, (size_t)NN * DIM * sizeof(float), stream);
      k_aggm<<<NEB, b256, 0, stream>>>(msgb, edstp, alphab, agg);
    } else {
      k_msgm<0,0><<<NEB, b256, 0, stream>>>(h2b, shb16, esrcp, edstp, w3T_l, wshT_l,
          aa_l, yb, nullptr, nullptr, logitsb, nullptr);
      k_alpha<<<(NN*NHEAD+255)/256, b256, 0, stream>>>(row_ptr, logitsb, alphab);
      hipMemsetAsync(agg, 0, (size_t)NN * DIM * sizeof(float), stream);
      k_msgm<1,0><<<NEB, b256, 0, stream>>>(h2b, shb16, esrcp, edstp, w3T_l, wshT_l,
          nullptr, yb, alphab, agg, nullptr, nullptr);
    }
    hipMemsetAsync(stacc, 0, (size_t)NN * 2 * sizeof(float), stream);
    k_gemmm<1,0,0,0,1><<<gemm_grid, b256, 0, stream>>>(agg, WoT_l, x, nullptr, nullptr,
        NN, DIM, DIM, DIM, stacc);                    // x += agg@Wo (+stats)
    k_finstat<<<(NN+255)/256, b256, 0, stream>>>(stacc, statsb, NN);
    k_gemmm<0,1,1,0,0><<<gemm_grid, b256, 0, stream>>>(x, F1T_l, agg, nullptr, statsb,
        NN, DIM, DIM, DIM, nullptr);                  // agg = silu(LN(x)@W1)
    hipMemsetAsync(stacc, 0, (size_t)NN * 2 * sizeof(float), stream);
    k_gemmm<1,0,0,0,1><<<gemm_grid, b256, 0, stream>>>(agg, F2T_l, x, nullptr, nullptr,
        NN, DIM, DIM, DIM, stacc);                    // x += agg@W2 (+stats)
    k_finstat<<<(NN+255)/256, b256, 0, stream>>>(stacc, statsb, NN);
  }

  // output head (needs 128-col stats — recompute)
  const __hip_bfloat16* H1T = bigWT + (size_t)24*512*480;
  const __hip_bfloat16* H2T = H1T + 128*128;
  k_stats<<<(NN+3)/4, b256, 0, stream>>>(x, statsb, NN, NS, DIM);
  k_gemmm<0,1,1,0,0><<<head_grid, b256, 0, stream>>>(x, H1T, agg, nullptr, statsb,
      NN, NS, NS, DIM, nullptr);
  k_gemmm<0,0,0,0,0><<<head_grid, b256, 0, stream>>>(agg, H2T, tmp, nullptr, nullptr,
      NN, NS, NS, NS, nullptr);
  hipMemsetAsync(d_out, 0, (size_t)NG * NS * sizeof(float), stream);
  k_scatter<<<(NN*NS+255)/256, b256, 0, stream>>>(tmp, batch, out);
}

// Round 19
// 2352.907 us; speedup vs baseline: 1.0185x; 1.0185x over previous
//
#include <hip/hip_runtime.h>
#include <hip/hip_bf16.h>
#include <math.h>

#define NN 10000
#define NE 160000
#define DIM 480
#define NSH 9
#define NBASIS 128
#define NHEAD 4
#define HDIM 120
#define NL 6
#define NG 256
#define NS 128
#define FCH 64
#define CUTOFF 5.0f
#define NEB 2500   // edge blocks (64 edges each)

typedef __attribute__((ext_vector_type(8))) short bf8v;
typedef __attribute__((ext_vector_type(4))) float f4v;

__device__ __forceinline__ float silu_f(float v) { return v / (1.0f + __expf(-v)); }
__device__ __forceinline__ float bf2f(ushort u) { return __uint_as_float(((unsigned)u) << 16); }
__device__ __forceinline__ ushort f2bfu(float f) {
  __hip_bfloat16 h = __float2bfloat16(f);
  return *reinterpret_cast<ushort*>(&h);
}

__device__ __forceinline__ void nt_store16(char* dst, uint4 v) {
  unsigned* p = (unsigned*)dst;
  __builtin_nontemporal_store(v.x, p + 0);
  __builtin_nontemporal_store(v.y, p + 1);
  __builtin_nontemporal_store(v.z, p + 2);
  __builtin_nontemporal_store(v.w, p + 3);
}
__device__ __forceinline__ uint4 nt_load16(const char* src) {
  const unsigned* p = (const unsigned*)src;
  uint4 v;
  v.x = __builtin_nontemporal_load(p + 0);
  v.y = __builtin_nontemporal_load(p + 1);
  v.z = __builtin_nontemporal_load(p + 2);
  v.w = __builtin_nontemporal_load(p + 3);
  return v;
}

struct bf16x4 { __hip_bfloat16 v[4]; };

// ---------------- CSR build ----------------
__global__ void k_zero_int(int* p, int n)
{
  int i = blockIdx.x * 256 + threadIdx.x;
  if (i < n) p[i] = 0;
}

__global__ void k_count(const int* __restrict__ edst, int* __restrict__ cnt)
{
  int e = blockIdx.x * 256 + threadIdx.x;
  if (e < NE) atomicAdd(&cnt[edst[e]], 1);
}

__global__ __launch_bounds__(1024)
void k_scan(const int* __restrict__ cnt, int* __restrict__ row_ptr)
{
  __shared__ int part[1024];
  int tid = threadIdx.x;
  const int per = 10;
  int base = tid * per;
  int s = 0;
  for (int i = 0; i < per; i++) { int idx = base + i; if (idx < NN) s += cnt[idx]; }
  part[tid] = s; __syncthreads();
  for (int off = 1; off < 1024; off <<= 1) {
    int v = (tid >= off) ? part[tid - off] : 0;
    __syncthreads();
    part[tid] += v;
    __syncthreads();
  }
  int run = (tid > 0) ? part[tid - 1] : 0;
  for (int i = 0; i < per; i++) {
    int idx = base + i;
    if (idx < NN) { row_ptr[idx] = run; run += cnt[idx]; }
  }
  if (tid == 1023) row_ptr[NN] = part[1023];
}

__global__ void k_fill(const int* __restrict__ edst, const int* __restrict__ row_ptr,
                       int* __restrict__ cursor, int* __restrict__ csr)
{
  int e = blockIdx.x * 256 + threadIdx.x;
  if (e >= NE) return;
  int d = edst[e];
  int p = atomicAdd(&cursor[d], 1);
  csr[row_ptr[d] + p] = e;
}

// ---------------- geometry in permuted (CSR) order; sh as bf16 [NE][16] padded ----
__global__ void k_geom_p(const float* __restrict__ pos, const int* __restrict__ esrc,
                         const int* __restrict__ edst, const int* __restrict__ csr,
                         __hip_bfloat16* __restrict__ shb, float* __restrict__ distp,
                         int* __restrict__ esrcp, int* __restrict__ edstp)
{
  int j = blockIdx.x * 256 + threadIdx.x;
  if (j >= NE) return;
  int e = csr[j];
  int s = esrc[e], d = edst[e];
  esrcp[j] = s;
  edstp[j] = d;
  float vx = pos[s*3+0] - pos[d*3+0];
  float vy = pos[s*3+1] - pos[d*3+1];
  float vz = pos[s*3+2] - pos[d*3+2];
  float r = sqrtf(vx*vx + vy*vy + vz*vz);
  distp[j] = r;
  float inv = 1.0f / (r + 1e-9f);
  float x = vx*inv, y = vy*inv, z = vz*inv;
  const float s3 = 1.7320508075688772f;
  const float s15 = 3.872983346207417f;
  const float s5 = 2.23606797749979f;
  float sv[9];
  sv[0] = 1.0f;
  sv[1] = s3*x; sv[2] = s3*y; sv[3] = s3*z;
  sv[4] = s15*x*y; sv[5] = s15*y*z; sv[6] = 0.5f*s5*(3.0f*z*z - 1.0f);
  sv[7] = s15*x*z; sv[8] = 0.5f*s15*(x*x - y*y);
  __hip_bfloat16* o = shb + (size_t)j * 16;
#pragma unroll
  for (int q = 0; q < 9; q++) o[q] = __float2bfloat16(sv[q]);
#pragma unroll
  for (int q = 9; q < 16; q++) o[q] = __float2bfloat16(0.f);
}

// ---------------- prep: w3T [7][512][64] + wshT [7][512][32] bf16 ----------------
__global__ void k_prep(const float* __restrict__ deg_w3, const float* __restrict__ rad_w3,
                       const float* __restrict__ W_deg_sh, const float* __restrict__ Wsh,
                       __hip_bfloat16* __restrict__ w3T, __hip_bfloat16* __restrict__ wshT)
{
  int i = blockIdx.x * 256 + threadIdx.x;
  if (i < 7*512*64) {
    int l = i / (512*64); int r = i - l*512*64; int col = r >> 6; int k = r & 63;
    float v = 0.f;
    if (col < DIM) {
      const float* src = (l == 0) ? deg_w3 : rad_w3 + (size_t)(l-1)*FCH*DIM;
      v = src[k*DIM + col];
    }
    w3T[i] = __float2bfloat16(v);
  }
  int j = i - 7*512*64;
  if (j >= 0 && j < 7*512*32) {
    int l = j / (512*32); int r = j - l*512*32; int col = r >> 5; int q = r & 31;
    float v = 0.f;
    if (col < DIM && q < 9) {
      const float* src = (l == 0) ? W_deg_sh : Wsh + (size_t)(l-1)*NSH*DIM;
      v = src[q*DIM + col];
    }
    wshT[j] = __float2bfloat16(v);
  }
}

// ---------------- prep: node-GEMM weights transposed bf16 ----------------
__global__ void k_prepw(const float* __restrict__ Wv, const float* __restrict__ Wo,
                        const float* __restrict__ f1, const float* __restrict__ f2,
                        const float* __restrict__ h1, const float* __restrict__ h2w,
                        __hip_bfloat16* __restrict__ WT)
{
  int i = blockIdx.x * 256 + threadIdx.x;
  const int big = 24*512*480;
  if (i < big) {
    int m = i / (512*480); int r = i - m*(512*480); int col = r / 480; int k = r - col*480;
    int l = m % 6; int t = m / 6;
    const float* src = (t==0 ? Wv : t==1 ? Wo : t==2 ? f1 : f2) + (size_t)l*DIM*DIM;
    float v = (col < DIM) ? src[k*DIM + col] : 0.f;
    WT[i] = __float2bfloat16(v);
  } else if (i < big + 2*128*128) {
    int j = i - big; int m = j / (128*128); int r = j - m*(128*128);
    int col = r >> 7; int k = r & 127;
    const float* src = m ? h2w : h1;
    WT[i] = __float2bfloat16(src[k*128 + col]);
  }
}

// ---------------- radial MLP -> h2 bf16 [E,64] ----------------
__global__ __launch_bounds__(256)
void k_radial(const float* __restrict__ dist, const float* __restrict__ w1,
              const float* __restrict__ w2, __hip_bfloat16* __restrict__ h2out)
{
  __shared__ float rbs[NBASIS][65];
  __shared__ float wsm[NBASIS * FCH];
  __shared__ float ds[64];
  int tid = threadIdx.x;
  int e0 = blockIdx.x * 64;
  if (tid < 64) ds[tid] = dist[e0 + tid];
  for (int i = tid; i < NBASIS * FCH; i += 256) wsm[i] = w1[i];
  __syncthreads();
  const float invw = (float)NBASIS / CUTOFF;
  for (int i = tid; i < NBASIS * 64; i += 256) {
    int k = i >> 6, e = i & 63;
    float c = k * (CUTOFF / 127.0f);
    float tt = (ds[e] - c) * invw;
    rbs[k][e] = __expf(-0.5f * tt * tt);
  }
  __syncthreads();
  int ty = tid >> 4, tx = tid & 15;
  float acc1[4][4] = {};
  for (int k = 0; k < NBASIS; k++) {
    float b[4];
#pragma unroll
    for (int j = 0; j < 4; j++) b[j] = wsm[k*FCH + tx*4 + j];
#pragma unroll
    for (int i = 0; i < 4; i++) {
      float a = rbs[k][ty*4 + i];
#pragma unroll
      for (int j = 0; j < 4; j++) acc1[i][j] = fmaf(a, b[j], acc1[i][j]);
    }
  }
  __syncthreads();
#pragma unroll
  for (int i = 0; i < 4; i++)
#pragma unroll
    for (int j = 0; j < 4; j++)
      rbs[tx*4 + j][ty*4 + i] = silu_f(acc1[i][j]);
  for (int i = tid; i < FCH * FCH; i += 256) wsm[i] = w2[i];
  __syncthreads();
  float acc2[4][4] = {};
  for (int k = 0; k < FCH; k++) {
    float b[4];
#pragma unroll
    for (int j = 0; j < 4; j++) b[j] = wsm[k*FCH + tx*4 + j];
#pragma unroll
    for (int i = 0; i < 4; i++) {
      float a = rbs[k][ty*4 + i];
#pragma unroll
      for (int j = 0; j < 4; j++) acc2[i][j] = fmaf(a, b[j], acc2[i][j]);
    }
  }
#pragma unroll
  for (int i = 0; i < 4; i++) {
    int e = e0 + ty*4 + i;
    bf16x4 p;
#pragma unroll
    for (int j = 0; j < 4; j++) p.v[j] = __float2bfloat16(silu_f(acc2[i][j]));
    *(bf16x4*)(h2out + (size_t)e*FCH + tx*4) = p;
  }
}

// ---------------- per-row LN stats (mu, rstd) — full read (init + head only) ----
__global__ __launch_bounds__(256)
void k_stats(const float* __restrict__ in, float* __restrict__ st,
             int n, int cols, int stride)
{
  int row = blockIdx.x * 4 + (threadIdx.x >> 6);
  int lane = threadIdx.x & 63;
  if (row >= n) return;
  const float* r = in + (size_t)row * stride;
  float s = 0.f, ss = 0.f;
  for (int c = lane; c < cols; c += 64) { float v = r[c]; s += v; ss += v*v; }
  for (int off = 32; off > 0; off >>= 1) { s += __shfl_down(s, off); ss += __shfl_down(ss, off); }
  if (lane == 0) {
    float mu = s / cols;
    float var = ss / cols - mu * mu;
    st[row*2]   = mu;
    st[row*2+1] = rsqrtf(fmaxf(var, 0.f) + 1e-5f);
  }
}

// ---------------- finalize fused stats: (sum,sumsq) -> (mu, rstd) ----------------
__global__ void k_finstat(const float* __restrict__ stacc, float* __restrict__ st, int n)
{
  int row = blockIdx.x * 256 + threadIdx.x;
  if (row >= n) return;
  float s = stacc[row*2], ss = stacc[row*2+1];
  float mu = s / DIM;
  float var = ss / DIM - mu * mu;
  st[row*2]   = mu;
  st[row*2+1] = rsqrtf(fmaxf(var, 0.f) + 1e-5f);
}

// ---------------- MFMA node GEMM: 64 rows x 128 cols; 1D grid with bijective
// XCD chunking, col-fastest within XCD so the 4 col-blocks sharing an A-row
// slice land on the SAME XCD's L2 (round-18 grid(157,4) round-robined them
// across XCDs -> A refetched ~4x). STATS=1 accumulates row (sum,sumsq). ----
template<int ADD, int SILU, int LNA, int OBF16, int STATS>
__global__ __launch_bounds__(256)
void k_gemmm(const float* __restrict__ A, const __hip_bfloat16* __restrict__ BT,
             float* __restrict__ C, __hip_bfloat16* __restrict__ Cb,
             const float* __restrict__ st, int M, int K, int Nc, int lda,
             float* __restrict__ stacc, int ncol)
{
  __shared__ __align__(16) char smA[4096];
  __shared__ __align__(16) char smB[8192];
  __shared__ float smu[64], srs[64];
  int tid = threadIdx.x;
  int lane = tid & 63;
  int wv = tid >> 6;
  int l15 = lane & 15, l4 = lane >> 4;

  int g = gridDim.x;
  int bid = blockIdx.x;
  int xcd = bid & 7;
  int q = g >> 3, r = g & 7;
  int basee = (xcd < r) ? xcd * (q + 1) : r * (q + 1) + (xcd - r) * q;
  int idx = basee + (bid >> 3);                 // bijective XCD chunking
  int row0 = (idx / ncol) * 64;
  int col0 = (idx % ncol) * 128;

  if (LNA && tid < 64) {
    int gr = row0 + tid;
    float m2 = 0.f, r2 = 1.f;
    if (gr < M) { m2 = st[gr*2]; r2 = st[gr*2+1]; }
    smu[tid] = m2; srs[tid] = r2;
  }
  f4v z4 = {0.f,0.f,0.f,0.f};
  f4v acc[8];
#pragma unroll
  for (int ct = 0; ct < 8; ct++) acc[ct] = z4;

  int arow = tid >> 2, aq = tid & 3;
  int bcol = tid >> 1, bh = tid & 1;
  for (int k0 = 0; k0 < K; k0 += 32) {
    __syncthreads();
    {
      int grow = row0 + arow;
      float f[8];
      if (grow < M) {
        const float* ap = A + (size_t)grow * lda + k0 + aq*8;
        float4 v0 = *(const float4*)ap;
        float4 v1 = *(const float4*)(ap + 4);
        f[0]=v0.x; f[1]=v0.y; f[2]=v0.z; f[3]=v0.w;
        f[4]=v1.x; f[5]=v1.y; f[6]=v1.z; f[7]=v1.w;
      } else {
#pragma unroll
        for (int qq = 0; qq < 8; qq++) f[qq] = 0.f;
      }
      if (LNA) {
        float mu = smu[arow], rs = srs[arow];
#pragma unroll
        for (int qq = 0; qq < 8; qq++) f[qq] = (f[qq] - mu) * rs;
      }
      unsigned u[4];
#pragma unroll
      for (int qq = 0; qq < 4; qq++)
        u[qq] = (unsigned)f2bfu(f[2*qq]) | ((unsigned)f2bfu(f[2*qq+1]) << 16);
      int base = arow*64 + aq*16;
      *(uint4*)(smA + (base ^ ((arow&7)<<4))) = make_uint4(u[0],u[1],u[2],u[3]);
    }
    {
      const ushort* bp = (const ushort*)BT + (size_t)(col0 + bcol) * K + k0 + bh*16;
      uint4 v0 = *(const uint4*)bp;
      uint4 v1 = *(const uint4*)(bp + 8);
      int base = bcol*64 + bh*32;
      *(uint4*)(smB + (base ^ ((bcol&7)<<4))) = v0;
      *(uint4*)(smB + ((base+16) ^ ((bcol&7)<<4))) = v1;
    }
    __syncthreads();
    int r0 = wv*16 + l15;
    bf8v a0 = *(const bf8v*)(smA + ((r0*64 + l4*16) ^ ((r0&7)<<4)));
#pragma unroll
    for (int ct = 0; ct < 8; ct++) {
      int cc = ct*16 + l15;
      bf8v b = *(const bf8v*)(smB + ((cc*64 + l4*16) ^ ((cc&7)<<4)));
      acc[ct] = __builtin_amdgcn_mfma_f32_16x16x32_bf16(a0, b, acc[ct], 0, 0, 0);
    }
  }
#pragma unroll
  for (int e = 0; e < 4; e++) {
    int row = row0 + wv*16 + l4*4 + e;
    float s = 0.f, ss = 0.f;
#pragma unroll
    for (int ct = 0; ct < 8; ct++) {
      int col = col0 + ct*16 + l15;
      if (row < M && col < Nc) {
        float v = acc[ct][e];
        if (SILU) v = silu_f(v);
        if (OBF16) Cb[(size_t)row * Nc + col] = __float2bfloat16(v);
        else {
          float* p = C + (size_t)row * Nc + col;
          float xn = ADD ? (*p + v) : v;
          *p = xn;
          if (STATS) { s += xn; ss += xn * xn; }
        }
      }
    }
    if (STATS) {
#pragma unroll
      for (int off = 1; off < 16; off <<= 1) {
        s  += __shfl_xor(s,  off, 16);
        ss += __shfl_xor(ss, off, 16);
      }
      if (l15 == 0 && row < M) {
        atomicAdd(&stacc[row*2],   s);
        atomicAdd(&stacc[row*2+1], ss);
      }
    }
  }
}

// ---------------- MFMA msg kernel, col-fused (round 17, unchanged) ----------------
template<int MODE, int STOREM>
__global__ __launch_bounds__(256)
void k_msgm(const __hip_bfloat16* __restrict__ h2, const __hip_bfloat16* __restrict__ shb,
            const int* __restrict__ esrcp, const int* __restrict__ edstp,
            const __hip_bfloat16* __restrict__ w3T, const __hip_bfloat16* __restrict__ wshT,
            const float* __restrict__ aa, const __hip_bfloat16* __restrict__ y,
            const float* __restrict__ alpha, float* __restrict__ outbuf,
            float* __restrict__ logits, __hip_bfloat16* __restrict__ msgb)
{
  __shared__ __align__(16) char sm_h2[8192];
  __shared__ __align__(16) char sm_w3[16384];
  __shared__ __align__(16) char sm_sh[4096];
  __shared__ __align__(16) char sm_wsh[8192];
  __shared__ int srcs[(MODE<=1)?64:1];
  __shared__ int dsts[(MODE>=1)?64:1];
  __shared__ int segidL[(MODE>=1)?64:1];
  __shared__ int seg_dstL[(MODE>=1)?32:1];

  int bid = blockIdx.x;
  int xcd = bid & 7;
  const int qq = NEB >> 3, rr = NEB & 7;
  int basee = (xcd < rr) ? xcd * (qq + 1) : rr * (qq + 1) + (xcd - rr) * qq;
  int eblk = basee + (bid >> 3);
  int e0 = eblk * 64;

  int tid = threadIdx.x;
  int lane = tid & 63;
  int wv = tid >> 6;
  int l15 = lane & 15, l4 = lane >> 4;
  int wrow0 = wv * 16;

  for (int c = tid; c < 512; c += 256) {
    int r = c >> 3, s = c & 7;
    uint4 v = *(const uint4*)((const char*)h2 + (size_t)(e0 + r) * 128 + s * 16);
    *(uint4*)(sm_h2 + ((r * 128 + s * 16) ^ ((r & 7) << 4))) = v;
  }
  {
    int r = tid >> 2, q = tid & 3;
    uint4 v = make_uint4(0u, 0u, 0u, 0u);
    if (q < 2)
      v = *(const uint4*)((const ushort*)shb + (size_t)(e0 + r) * 16 + q * 8);
    *(uint4*)(sm_sh + ((r * 64 + q * 16) ^ ((r & 7) << 4))) = v;
  }
  if (tid < 64) {
    if (MODE <= 1) srcs[tid] = esrcp[e0 + tid];
    if (MODE >= 1) dsts[tid] = edstp[e0 + tid];
  }
  __syncthreads();

  int nseg = 0;
  if (MODE >= 1) {
    if (tid < 64) {
      bool flag = (tid == 0) || (dsts[tid] != dsts[tid - 1]);
      unsigned long long m = __ballot(flag ? 1 : 0);
      unsigned long long below = m & (~0ull >> (63 - tid));
      int sg = __popcll(below) - 1;
      segidL[tid] = sg;
      if (flag && sg < 32) seg_dstL[sg] = dsts[tid];
    }
    __syncthreads();
    nseg = segidL[63] + 1;
  }

  int srcs4[4];
  float4 al4[4];
#pragma unroll
  for (int e = 0; e < 4; e++) {
    int rl = wrow0 + l4 * 4 + e;
    if (MODE <= 1) srcs4[e] = srcs[rl];
    if (MODE == 1) al4[e] = *(const float4*)(alpha + (size_t)(e0 + rl) * 4);
  }

  const ushort* yus = (const ushort*)y;
  f4v z4 = {0.f, 0.f, 0.f, 0.f};
  float lacc[4][4];
  if (MODE == 0) {
#pragma unroll
    for (int e = 0; e < 4; e++)
#pragma unroll
      for (int h = 0; h < 4; h++) lacc[e][h] = 0.f;
  }

#pragma unroll
  for (int ci = 0; ci < 4; ci++) {
    int col0 = ci * 128;
    __syncthreads();
    for (int c = tid; c < 1024; c += 256) {
      int r = c >> 3, s = c & 7;
      uint4 v = *(const uint4*)((const char*)w3T + (size_t)(col0 + r) * 128 + s * 16);
      *(uint4*)(sm_w3 + ((r * 128 + s * 16) ^ ((r & 7) << 4))) = v;
    }
    for (int c = tid; c < 512; c += 256) {
      int r = c >> 2, q = c & 3;
      uint4 v = *(const uint4*)((const ushort*)wshT + (size_t)(col0 + r) * 32 + q * 8);
      *(uint4*)(sm_wsh + ((r * 64 + q * 16) ^ ((r & 7) << 4))) = v;
    }
    __syncthreads();

    f4v g[8];
#pragma unroll
    for (int ct = 0; ct < 8; ct++) g[ct] = z4;

#pragma unroll
    for (int ks = 0; ks < 2; ks++) {
      int k0b = (ks * 32 + l4 * 8) * 2;
      int r0 = wrow0 + l15;
      bf8v a0 = *(const bf8v*)(sm_h2 + ((r0 * 128 + k0b) ^ ((r0 & 7) << 4)));
#pragma unroll
      for (int ct = 0; ct < 8; ct++) {
        int cc = ct * 16 + l15;
        bf8v b = *(const bf8v*)(sm_w3 + ((cc * 128 + k0b) ^ ((cc & 7) << 4)));
        g[ct] = __builtin_amdgcn_mfma_f32_16x16x32_bf16(a0, b, g[ct], 0, 0, 0);
      }
    }

    {
      int r0 = wrow0 + l15;
      bf8v shA = *(const bf8v*)(sm_sh + ((r0 * 64 + l4 * 16) ^ ((r0 & 7) << 4)));
#pragma unroll
      for (int ct = 0; ct < 8; ct++) {
        int cc = ct * 16 + l15;
        int col = col0 + cc;
        bf8v wB = *(const bf8v*)(sm_wsh + ((cc * 64 + l4 * 16) ^ ((cc & 7) << 4)));
        f4v sw4 = __builtin_amdgcn_mfma_f32_16x16x32_bf16(shA, wB, z4, 0, 0, 0);
#pragma unroll
        for (int e = 0; e < 4; e++) {
          float yv;
          if (MODE == 2) yv = 1.f;
          else yv = (col < DIM) ? bf2f(yus[(size_t)srcs4[e] * DIM + col]) : 0.f;
          float mv = yv * sw4[e] * g[ct][e];
          if (MODE == 1) {
            float av = (col < 120) ? al4[e].x : (col < 240) ? al4[e].y
                     : (col < 360) ? al4[e].z : al4[e].w;
            mv *= av;
          }
          if (MODE == 2) mv *= (1.0f / 16.0f);
          g[ct][e] = mv;
        }
      }
    }

    if (MODE == 0) {
      float aav[8];
#pragma unroll
      for (int ct = 0; ct < 8; ct++) {
        int col = col0 + ct * 16 + l15;
        aav[ct] = (col < DIM) ? aa[col] : 0.f;
      }
#pragma unroll
      for (int e = 0; e < 4; e++) {
        float sA = 0.f, sB = 0.f;
#pragma unroll
        for (int ct = 0; ct < 8; ct++) {
          int col = col0 + ct * 16 + l15;
          float mv = g[ct][e];
          float lv = (mv > 0.f) ? mv : 0.2f * mv;
          float c = lv * aav[ct];
          if (col / 120 == ci) sA += c; else sB += c;
        }
#pragma unroll
        for (int off = 1; off < 16; off <<= 1) {
          sA += __shfl_xor(sA, off, 16);
          sB += __shfl_xor(sB, off, 16);
        }
        lacc[e][ci] += sA;
        if (ci < 3) lacc[e][ci + 1] += sB;
      }
      if (STOREM) {
        __syncthreads();
#pragma unroll
        for (int ct = 0; ct < 8; ct++) {
          int cc = ct * 16 + l15;
          int ebase = wrow0 + l4 * 4;
          ushort4 pk;
          pk.x = f2bfu(g[ct][0]); pk.y = f2bfu(g[ct][1]);
          pk.z = f2bfu(g[ct][2]); pk.w = f2bfu(g[ct][3]);
          *(ushort4*)(sm_w3 + ((cc * 128 + ebase * 2) ^ ((cc & 7) << 4))) = pk;
        }
        __syncthreads();
        char* gdst = (char*)msgb + (size_t)(eblk * 4 + ci) * 16384;
#pragma unroll
        for (int k = 0; k < 4; k++) {
          int o = tid * 16 + k * 4096;
          uint4 v = *(const uint4*)(sm_w3 + o);
          nt_store16(gdst + o, v);
        }
      }
    } else if (nseg > 32) {
#pragma unroll
      for (int e = 0; e < 4; e++) {
        int rl = wrow0 + l4 * 4 + e;
        int dd = dsts[rl];
#pragma unroll
        for (int ct = 0; ct < 8; ct++) {
          int col = col0 + ct * 16 + l15;
          if (col < DIM) atomicAdd(&outbuf[(size_t)dd * DIM + col], g[ct][e]);
        }
      }
    } else {
      __syncthreads();
#pragma unroll
      for (int ct = 0; ct < 8; ct++) {
        int cc = ct * 16 + l15;
        int ebase = wrow0 + l4 * 4;
        ushort4 pk;
        pk.x = f2bfu(g[ct][0]); pk.y = f2bfu(g[ct][1]);
        pk.z = f2bfu(g[ct][2]); pk.w = f2bfu(g[ct][3]);
        *(ushort4*)(sm_w3 + ((cc * 128 + ebase * 2) ^ ((cc & 7) << 4))) = pk;
      }
      __syncthreads();
      f4v p[2][2];
      p[0][0] = z4; p[0][1] = z4; p[1][0] = z4; p[1][1] = z4;
#pragma unroll
      for (int ks = 0; ks < 2; ks++) {
        int k0 = ks * 32 + l4 * 8;
        bf8v a0, a1;
#pragma unroll
        for (int e2 = 0; e2 < 8; e2++) {
          int sg = segidL[k0 + e2];
          a0[e2] = (sg == l15)      ? (short)0x3F80 : (short)0;
          a1[e2] = (sg == l15 + 16) ? (short)0x3F80 : (short)0;
        }
#pragma unroll
        for (int c2 = 0; c2 < 2; c2++) {
          int cc = (wv * 2 + c2) * 16 + l15;
          bf8v bm = *(const bf8v*)(sm_w3 + ((cc * 128 + k0 * 2) ^ ((cc & 7) << 4)));
          p[0][c2] = __builtin_amdgcn_mfma_f32_16x16x32_bf16(a0, bm, p[0][c2], 0, 0, 0);
          p[1][c2] = __builtin_amdgcn_mfma_f32_16x16x32_bf16(a1, bm, p[1][c2], 0, 0, 0);
        }
      }
#pragma unroll
      for (int rt = 0; rt < 2; rt++)
#pragma unroll
      for (int c2 = 0; c2 < 2; c2++)
#pragma unroll
      for (int e = 0; e < 4; e++) {
        int seg = rt * 16 + l4 * 4 + e;
        int col = col0 + (wv * 2 + c2) * 16 + l15;
        if (seg < nseg && col < DIM) {
          float v = p[rt][c2][e];
          float* ptr = outbuf + (size_t)seg_dstL[seg] * DIM + col;
          if (seg == 0 || seg == nseg - 1) atomicAdd(ptr, v);
          else if (MODE == 1) *ptr = v;
          else *ptr += v;
        }
      }
    }
  }

  if (MODE == 0) {
#pragma unroll
    for (int e = 0; e < 4; e++) {
      int row = e0 + wrow0 + l4 * 4 + e;
      if (l15 == 0) {
        logits[(size_t)row * 4 + 0] = lacc[e][0];
        logits[(size_t)row * 4 + 1] = lacc[e][1];
        logits[(size_t)row * 4 + 2] = lacc[e][2];
        logits[(size_t)row * 4 + 3] = lacc[e][3];
      }
    }
  }
}

// ---------------- pass B, col-fused: 2500 blocks x 4 chunks ----------------
__global__ __launch_bounds__(256)
void k_aggm(const __hip_bfloat16* __restrict__ msgb, const int* __restrict__ edstp,
            const float* __restrict__ alpha, float* __restrict__ agg)
{
  __shared__ __align__(16) char smM[16384];
  __shared__ __align__(16) float alsq[64][4];
  __shared__ int dsts[64];
  __shared__ int segidL[64];
  __shared__ int seg_dstL[32];

  int bid = blockIdx.x;
  int xcd = bid & 7;
  const int qq = NEB >> 3, rr = NEB & 7;
  int basee = (xcd < rr) ? xcd * (qq + 1) : rr * (qq + 1) + (xcd - rr) * qq;
  int eblk = basee + (bid >> 3);
  int e0 = eblk * 64;

  int tid = threadIdx.x;
  int lane = tid & 63;
  int wv = tid >> 6;
  int l15 = lane & 15, l4 = lane >> 4;

  if (tid < 64) {
    dsts[tid] = edstp[e0 + tid];
    *(float4*)&alsq[tid][0] = *(const float4*)(alpha + (size_t)(e0 + tid) * 4);
  }
  __syncthreads();

  int nseg = 0;
  if (tid < 64) {
    bool flag = (tid == 0) || (dsts[tid] != dsts[tid - 1]);
    unsigned long long m = __ballot(flag ? 1 : 0);
    unsigned long long below = m & (~0ull >> (63 - tid));
    int sg = __popcll(below) - 1;
    segidL[tid] = sg;
    if (flag && sg < 32) seg_dstL[sg] = dsts[tid];
  }
  __syncthreads();
  nseg = segidL[63] + 1;

  f4v z4 = {0.f,0.f,0.f,0.f};
#pragma unroll
  for (int ci = 0; ci < 4; ci++) {
    int col0 = ci * 128;
    __syncthreads();
    const char* gsrc = (const char*)msgb + (size_t)(eblk * 4 + ci) * 16384;
    uint4 vv[4];
#pragma unroll
    for (int k = 0; k < 4; k++) {
      int o = tid * 16 + k * 4096;
      uint4 v = nt_load16(gsrc + o);
      int cc = o >> 7;
      int col = col0 + cc;
      int h = (col < DIM) ? (col / 120) : 3;
      int be = ((o & 127) ^ ((cc & 7) << 4)) >> 1;
      unsigned w[4] = {v.x, v.y, v.z, v.w};
#pragma unroll
      for (int q = 0; q < 4; q++) {
        float lo = bf2f((ushort)(w[q] & 0xffffu)) * alsq[be + 2*q][h];
        float hi = bf2f((ushort)(w[q] >> 16))     * alsq[be + 2*q + 1][h];
        w[q] = (unsigned)f2bfu(lo) | ((unsigned)f2bfu(hi) << 16);
      }
      vv[k] = make_uint4(w[0], w[1], w[2], w[3]);
      *(uint4*)(smM + o) = vv[k];
    }
    __syncthreads();

    if (nseg > 32) {
#pragma unroll
      for (int k = 0; k < 4; k++) {
        int o = tid * 16 + k * 4096;
        int cc = o >> 7;
        int col = col0 + cc;
        if (col >= DIM) continue;
        int be = ((o & 127) ^ ((cc & 7) << 4)) >> 1;
        unsigned w[4] = {vv[k].x, vv[k].y, vv[k].z, vv[k].w};
#pragma unroll
        for (int q = 0; q < 4; q++) {
          atomicAdd(&agg[(size_t)dsts[be + 2*q]   * DIM + col], bf2f((ushort)(w[q] & 0xffffu)));
          atomicAdd(&agg[(size_t)dsts[be + 2*q+1] * DIM + col], bf2f((ushort)(w[q] >> 16)));
        }
      }
      continue;
    }

    f4v p[2][2];
    p[0][0] = z4; p[0][1] = z4; p[1][0] = z4; p[1][1] = z4;
#pragma unroll
    for (int ks = 0; ks < 2; ks++) {
      int k0 = ks * 32 + l4 * 8;
      bf8v a0, a1;
#pragma unroll
      for (int e2 = 0; e2 < 8; e2++) {
        int sg = segidL[k0 + e2];
        a0[e2] = (sg == l15)      ? (short)0x3F80 : (short)0;
        a1[e2] = (sg == l15 + 16) ? (short)0x3F80 : (short)0;
      }
#pragma unroll
      for (int c2 = 0; c2 < 2; c2++) {
        int cc = (wv * 2 + c2) * 16 + l15;
        bf8v bm = *(const bf8v*)(smM + ((cc * 128 + k0 * 2) ^ ((cc & 7) << 4)));
        p[0][c2] = __builtin_amdgcn_mfma_f32_16x16x32_bf16(a0, bm, p[0][c2], 0, 0, 0);
        p[1][c2] = __builtin_amdgcn_mfma_f32_16x16x32_bf16(a1, bm, p[1][c2], 0, 0, 0);
      }
    }
#pragma unroll
    for (int rt = 0; rt < 2; rt++)
#pragma unroll
    for (int c2 = 0; c2 < 2; c2++)
#pragma unroll
    for (int e = 0; e < 4; e++) {
      int seg = rt * 16 + l4 * 4 + e;
      int col = col0 + (wv * 2 + c2) * 16 + l15;
      if (seg < nseg && col < DIM) {
        float v = p[rt][c2][e];
        float* ptr = agg + (size_t)seg_dstL[seg] * DIM + col;
        if (seg == 0 || seg == nseg - 1) atomicAdd(ptr, v);
        else *ptr = v;
      }
    }
  }
}

// ---------------- segment softmax ----------------
__global__ void k_alpha(const int* __restrict__ row_ptr, const float* __restrict__ logits,
                        float* __restrict__ alpha)
{
  int i = blockIdx.x * 256 + threadIdx.x;
  if (i >= NN * NHEAD) return;
  int d = i >> 2, h = i & 3;
  int beg = row_ptr[d], end = row_ptr[d+1];
  if (beg == end) return;
  float m = -1e30f;
  for (int j = beg; j < end; j++) m = fmaxf(m, logits[(size_t)j*NHEAD + h]);
  float s = 0.f;
  for (int j = beg; j < end; j++) {
    float ex = __expf(logits[(size_t)j*NHEAD + h] - m);
    alpha[(size_t)j*NHEAD + h] = ex;
    s += ex;
  }
  float inv = 1.f / (s + 1e-9f);
  for (int j = beg; j < end; j++) alpha[(size_t)j*NHEAD + h] *= inv;
}

// ---------------- x init ----------------
__global__ void k_init_x(const int* __restrict__ z, const float* __restrict__ emb,
                         float* __restrict__ x)
{
  int i = blockIdx.x * 256 + threadIdx.x;
  if (i >= NN * DIM) return;
  int n = i / DIM, c = i - n * DIM;
  x[i] = emb[(size_t)z[n]*DIM + c];
}

// ---------------- final scatter ----------------
__global__ void k_scatter(const float* __restrict__ h, const int* __restrict__ batch,
                          float* __restrict__ out)
{
  int i = blockIdx.x * 256 + threadIdx.x;
  if (i >= NN * NS) return;
  int n = i >> 7;
  atomicAdd(&out[(size_t)batch[n]*NS + (i & 127)], h[i] * 0.23570226039551584f);
}

extern "C" void kernel_launch(void* const* d_in, const int* in_sizes, int n_in,
                              void* d_out, int out_size, void* d_ws, size_t ws_size,
                              hipStream_t stream)
{
  const int*   z        = (const int*)  d_in[0];
  const float* pos      = (const float*)d_in[1];
  const int*   batch    = (const int*)  d_in[2];
  const int*   esrc     = (const int*)  d_in[3];
  const int*   edst     = (const int*)  d_in[4];
  const float* atom_emb = (const float*)d_in[5];
  const float* W_deg_sh = (const float*)d_in[6];
  const float* deg_w1   = (const float*)d_in[7];
  const float* deg_w2   = (const float*)d_in[8];
  const float* deg_w3   = (const float*)d_in[9];
  const float* Wv       = (const float*)d_in[10];
  const float* Wsh      = (const float*)d_in[11];
  const float* rad_w1   = (const float*)d_in[12];
  const float* rad_w2   = (const float*)d_in[13];
  const float* rad_w3   = (const float*)d_in[14];
  const float* attn_a   = (const float*)d_in[15];
  const float* Wo       = (const float*)d_in[16];
  const float* ffn_w1   = (const float*)d_in[17];
  const float* ffn_w2   = (const float*)d_in[18];
  const float* head_w1  = (const float*)d_in[19];
  const float* head_w2  = (const float*)d_in[20];
  float* out = (float*)d_out;

  float* x      = (float*)d_ws;
  float* statsb = x      + (size_t)NN * DIM;
  float* stacc  = statsb + (size_t)NN * 2;
  float* agg    = stacc  + (size_t)NN * 2;
  float* distp  = agg    + (size_t)NN * DIM;
  float* logitsb= distp  + (size_t)NE;
  float* alphab = logitsb+ (size_t)NE * NHEAD * 2;
  __hip_bfloat16* yb    = (__hip_bfloat16*)(alphab + (size_t)NE * NHEAD);
  __hip_bfloat16* h2b   = yb + (size_t)NN * DIM;
  __hip_bfloat16* shb16 = h2b + (size_t)NE * FCH;
  __hip_bfloat16* w3Tb  = shb16 + (size_t)NE * 16;
  __hip_bfloat16* wshTb = w3Tb + (size_t)7 * 512 * 64;
  __hip_bfloat16* bigWT = wshTb + (size_t)7 * 512 * 32;
  int* cnt      = (int*)(bigWT + (size_t)24*512*480 + 2*128*128);
  int* row_ptr  = cnt + NN;
  int* csr      = row_ptr + NN + 1;
  int* cursor   = csr + NE;
  int* esrcp    = cursor + NN;
  int* edstp    = esrcp + NE;
  __hip_bfloat16* msgb = (__hip_bfloat16*)(edstp + NE);
  float* tmp = logitsb;

  size_t needed = (size_t)((char*)msgb + (size_t)10000 * 16384 - (char*)d_ws);
  bool fast = ws_size >= needed;

  dim3 b256(256);
  k_zero_int<<<(NN+255)/256, b256, 0, stream>>>(cnt, NN);
  k_count<<<(NE+255)/256, b256, 0, stream>>>(edst, cnt);
  k_scan<<<1, 1024, 0, stream>>>(cnt, row_ptr);
  k_zero_int<<<(NN+255)/256, b256, 0, stream>>>(cursor, NN);
  k_fill<<<(NE+255)/256, b256, 0, stream>>>(edst, row_ptr, cursor, csr);
  k_geom_p<<<(NE+255)/256, b256, 0, stream>>>(pos, esrc, edst, csr, shb16, distp, esrcp, edstp);
  k_prep<<<(7*512*64 + 7*512*32 + 255)/256, b256, 0, stream>>>(deg_w3, rad_w3, W_deg_sh, Wsh,
      w3Tb, wshTb);
  k_prepw<<<(24*512*480 + 2*128*128 + 255)/256, b256, 0, stream>>>(Wv, Wo, ffn_w1, ffn_w2,
      head_w1, head_w2, bigWT);

  // degree embedding
  k_radial<<<NE/64, b256, 0, stream>>>(distp, deg_w1, deg_w2, h2b);
  k_init_x<<<(NN*DIM+255)/256, b256, 0, stream>>>(z, atom_emb, x);
  k_msgm<2,0><<<NEB, b256, 0, stream>>>(h2b, shb16, esrcp, edstp, w3Tb, wshTb,
      nullptr, nullptr, nullptr, x, nullptr, nullptr);
  k_stats<<<(NN+3)/4, b256, 0, stream>>>(x, statsb, NN, DIM, DIM);

  const int G4 = 157 * 4;   // 628 blocks, ncol=4
  const int G1 = 157;       // head, ncol=1
  for (int l = 0; l < NL; l++) {
    const float* w1_l  = rad_w1 + (size_t)l*NBASIS*FCH;
    const float* w2_l  = rad_w2 + (size_t)l*FCH*FCH;
    const float* aa_l  = attn_a + (size_t)l*NHEAD*HDIM;
    const __hip_bfloat16* w3T_l  = w3Tb  + (size_t)(l+1)*512*64;
    const __hip_bfloat16* wshT_l = wshTb + (size_t)(l+1)*512*32;
    const __hip_bfloat16* WvT_l = bigWT + (size_t)(0+l)*512*480;
    const __hip_bfloat16* WoT_l = bigWT + (size_t)(6+l)*512*480;
    const __hip_bfloat16* F1T_l = bigWT + (size_t)(12+l)*512*480;
    const __hip_bfloat16* F2T_l = bigWT + (size_t)(18+l)*512*480;

    k_gemmm<0,0,1,1,0><<<G4, b256, 0, stream>>>(x, WvT_l, nullptr, yb, statsb,
        NN, DIM, DIM, DIM, nullptr, 4);
    k_radial<<<NE/64, b256, 0, stream>>>(distp, w1_l, w2_l, h2b);
    if (fast) {
      k_msgm<0,1><<<NEB, b256, 0, stream>>>(h2b, shb16, esrcp, edstp, w3T_l, wshT_l,
          aa_l, yb, nullptr, nullptr, logitsb, msgb);
      k_alpha<<<(NN*NHEAD+255)/256, b256, 0, stream>>>(row_ptr, logitsb, alphab);
      hipMemsetAsync(agg, 0, (size_t)NN * DIM * sizeof(float), stream);
      k_aggm<<<NEB, b256, 0, stream>>>(msgb, edstp, alphab, agg);
    } else {
      k_msgm<0,0><<<NEB, b256, 0, stream>>>(h2b, shb16, esrcp, edstp, w3T_l, wshT_l,
          aa_l, yb, nullptr, nullptr, logitsb, nullptr);
      k_alpha<<<(NN*NHEAD+255)/256, b256, 0, stream>>>(row_ptr, logitsb, alphab);
      hipMemsetAsync(agg, 0, (size_t)NN * DIM * sizeof(float), stream);
      k_msgm<1,0><<<NEB, b256, 0, stream>>>(h2b, shb16, esrcp, edstp, w3T_l, wshT_l,
          nullptr, yb, alphab, agg, nullptr, nullptr);
    }
    hipMemsetAsync(stacc, 0, (size_t)NN * 2 * sizeof(float), stream);
    k_gemmm<1,0,0,0,1><<<G4, b256, 0, stream>>>(agg, WoT_l, x, nullptr, nullptr,
        NN, DIM, DIM, DIM, stacc, 4);
    k_finstat<<<(NN+255)/256, b256, 0, stream>>>(stacc, statsb, NN);
    k_gemmm<0,1,1,0,0><<<G4, b256, 0, stream>>>(x, F1T_l, agg, nullptr, statsb,
        NN, DIM, DIM, DIM, nullptr, 4);
    hipMemsetAsync(stacc, 0, (size_t)NN * 2 * sizeof(float), stream);
    k_gemmm<1,0,0,0,1><<<G4, b256, 0, stream>>>(agg, F2T_l, x, nullptr, nullptr,
        NN, DIM, DIM, DIM, stacc, 4);
    k_finstat<<<(NN+255)/256, b256, 0, stream>>>(stacc, statsb, NN);
  }

  // output head (128-col stats — recompute)
  const __hip_bfloat16* H1T = bigWT + (size_t)24*512*480;
  const __hip_bfloat16* H2T = H1T + 128*128;
  k_stats<<<(NN+3)/4, b256, 0, stream>>>(x, statsb, NN, NS, DIM);
  k_gemmm<0,1,1,0,0><<<G1, b256, 0, stream>>>(x, H1T, agg, nullptr, statsb,
      NN, NS, NS, DIM, nullptr, 1);
  k_gemmm<0,0,0,0,0><<<G1, b256, 0, stream>>>(agg, H2T, tmp, nullptr, nullptr,
      NN, NS, NS, NS, nullptr, 1);
  hipMemsetAsync(d_out, 0, (size_t)NG * NS * sizeof(float), stream);
  k_scatter<<<(NN*NS+255)/256, b256, 0, stream>>>(tmp, batch, out);
}